// Round 8
// baseline (181.756 us; speedup 1.0000x reference)
//
#include <hip/hip_runtime.h>
#include <hip/hip_bf16.h>
#include <stdint.h>

#define N_PTS   4096
#define M_CODES 4096
#define ZDIM    1024
// fp8 tiled layout: elem (r,k) at seg(rb)*16384 + kg*128 + r16*8 + ke  (BYTES)
//   rb=r>>4, r16=r&15, kg=k>>3, ke=k&7. Chunk (rb,kg) = 16 rows x 8 k = 128 B.
//   Seg = 16 rows x 1024 k x 1 B = 16 KB.

typedef __attribute__((ext_vector_type(4)))  float f32x4;
typedef __attribute__((ext_vector_type(16))) float f32x16;
typedef __attribute__((ext_vector_type(8)))  int   i32x8;

__device__ __forceinline__ unsigned enc_f32(float f) {
    unsigned u = __float_as_uint(f);
    return (u & 0x80000000u) ? ~u : (u | 0x80000000u);
}
__device__ __forceinline__ float dec_f32(unsigned e) {
    unsigned u = (e & 0x80000000u) ? (e ^ 0x80000000u) : ~e;
    return __uint_as_float(u);
}

// ---------------------------------------------------------------------------
// prep: fp32 -> fp8 e4m3 (OCP) + tiled layout + row sum-of-squares (fp32,
// pre-quantization — error enters as 2(e.dz+z.de), sigma~2 << 35.5 threshold).
// One block = 16 rows. grid 512 (256 z + 256 e).
// ---------------------------------------------------------------------------
#define PREP_PITCH_B 1040   // bytes per LDS row: 1024 + 16 pad
__global__ __launch_bounds__(256) void prep_kernel(
    const float* __restrict__ z, const float* __restrict__ e,
    uint8_t* __restrict__ zb, uint8_t* __restrict__ eb,
    float* __restrict__ zsq, float* __restrict__ esq,
    unsigned* __restrict__ min_enc) {
    __shared__ uint8_t tile[16 * PREP_PITCH_B];   // ~16.6 KB
    __shared__ float redbuf[16 * 4];

    const int t = threadIdx.x;
    const int b = blockIdx.x;
    if (b < 16) min_enc[b * 256 + t] = 0xFFFFFFFFu;

    const bool is_z = b < 256;
    const int rb = b & 255;
    const float* src = (is_z ? z : e) + (size_t)rb * 16 * ZDIM;
    uint8_t* dst = (is_z ? zb : eb) + (size_t)rb * 16384;   // 16 KB seg
    const int w = t >> 6, lane = t & 63;

    // Phase 1: coalesced loads, fp32 row sums (R8-proven reduction),
    // pack 4 floats -> 4 fp8 into one dword in LDS.
    #pragma unroll
    for (int it = 0; it < 16; it++) {
        float4 v = reinterpret_cast<const float4*>(src + (size_t)it * ZDIM)[t];
        int pk = 0;
        pk = __builtin_amdgcn_cvt_pk_fp8_f32(v.x, v.y, pk, false);
        pk = __builtin_amdgcn_cvt_pk_fp8_f32(v.z, v.w, pk, true);
        *reinterpret_cast<int*>(&tile[it * PREP_PITCH_B + t * 4]) = pk;
        float s = v.x * v.x + v.y * v.y + v.z * v.z + v.w * v.w;
        #pragma unroll
        for (int off = 1; off < 64; off <<= 1) s += __shfl_xor(s, off, 64);
        if (lane == 0) redbuf[it * 4 + w] = s;
    }
    __syncthreads();

    // Phase 2: transpose-store to tiled global (chunk c -> dst + c*8, linear).
    #pragma unroll
    for (int it2 = 0; it2 < 8; it2++) {
        const int c = it2 * 256 + t;          // 0..2047
        const int kg = c >> 4, r16 = c & 15;
        const unsigned long long val = *reinterpret_cast<const unsigned long long*>(
            &tile[r16 * PREP_PITCH_B + kg * 8]);
        *reinterpret_cast<unsigned long long*>(&dst[(size_t)c * 8]) = val;
    }
    if (t < 16) {
        float sq = redbuf[t * 4] + redbuf[t * 4 + 1] +
                   redbuf[t * 4 + 2] + redbuf[t * 4 + 3];
        const int row = rb * 16 + t;
        if (is_z) zsq[row] = sq; else esq[row] = sq;
    }
}

// ---------------------------------------------------------------------------
// gemm_min: R7 champion (32x32x64 MX, 16 stages, 3 x 8 KB triple buffer,
// depth-2 DMA, counted-vmcnt + raw s_barrier boundaries) + two in-regime
// latency fixes:
//   (1) B REGISTER DOUBLE-BUFFER: B(st+1) fragments prefetched at the top
//       of stage st; MFMAs consume B(st) already in registers -> B's L2
//       latency (~200-300 cyc, exposed right after each barrier in R7)
//       moves off the critical path. FIFO per stage: B-prefetch 8 ops +
//       DMA 2 ops -> boundary wait vmcnt(10) (retires DMA(st+1), keeps
//       B(st+1)+DMA(st+2) in flight); st=14 boundary vmcnt(8) (no DMA(16)).
//       Prologue: DMA(0),DMA(1),B(0) = 12 outstanding -> vmcnt(10) retires
//       DMA(0) only. bc<-bn copies are in fully-unrolled straight-line code
//       -> SSA renaming removes them (rule #20 respected: all names static).
//   (2) T5 s_setprio(1) around the MFMA cluster — this structure has the
//       counted-vmcnt role-split (load-issuing vs MFMA-entering waves)
//       where T5 measured +21-39%; null only on drain-0 structures.
// VGPR: acc 64 + bc 16 + bn 16 + af 8 + addr ~20 ~= 124 < 128 -> (256,4),
// 4 blocks/CU, no spill (WRITE_SIZE is the tripwire).
// Everything else (layouts, epilogue, DMA mapping) unchanged from R7.
// ---------------------------------------------------------------------------
__global__ __launch_bounds__(256, 4) void gemm_min_kernel(
    const uint8_t* __restrict__ zb, const uint8_t* __restrict__ eb,
    const float* __restrict__ zsq, unsigned* __restrict__ min_enc) {
    __shared__ __align__(16) uint8_t As[3 * 8192];   // 3 bufs x (8 segs x 1 KB)
    __shared__ float zsq_s[128];
    __shared__ float colmin[2][128];

    const int t = threadIdx.x;        // 0..255
    const int bx = blockIdx.x;        // code (col) block
    const int by = blockIdx.y;        // point (row) block
    const int lane = t & 63;
    const int w = t >> 6;             // 0..3
    const int wm = w >> 1, wn = w & 1;
    const int hi = lane >> 5;         // K-half selector (and C/D row offset)

    if (t < 128) zsq_s[t] = zsq[by * 128 + t];

    f32x16 acc[2][2];
    #pragma unroll
    for (int i = 0; i < 2; i++)
        #pragma unroll
        for (int j = 0; j < 2; j++)
            #pragma unroll
            for (int r = 0; r < 16; r++) acc[i][j][r] = 0.f;

    const size_t a_seg0 = (size_t)(by * 8) * 16384;

    // Per-lane operand offset within a seg's 1 KB K-stage window:
    // lane l: k = (l>>5)*32 + p*8 + ke -> (l>>5)*512 + p*128 + (l&15)*8;
    // rows 16..31 of the 32-row block live one seg over (seg_sel).
    const int seg_sel = (lane & 31) >> 4;
    const int op_off  = hi * 512 + (lane & 15) * 8;
    const int a_off   = seg_sel * 1024 + op_off;

    // B (global): wave wn's 64-col panel; an adds 2 segs (32 KB).
    const uint8_t* b_frag =
        eb + (size_t)(bx * 8 + wn * 4 + seg_sel) * 16384 + op_off;

    // A staging per stage: 8 segs x 1 KB runs (seg's K-window st*1024).
    // 2 instrs x 256 thr x 16 B = 8 KB. Instr j: wave w -> seg j*4+w.
#define DMA_STAGE(st_)                                                        \
    {                                                                         \
        const int buf_ = ((st_) % 3) * 8192;                                  \
        _Pragma("unroll")                                                     \
        for (int j = 0; j < 2; j++) {                                         \
            const int seg_ = j * 4 + w;                                       \
            const uint8_t* ga = zb + a_seg0 + (size_t)seg_ * 16384 +          \
                (st_) * 1024 + lane * 16;                                     \
            __builtin_amdgcn_global_load_lds(                                 \
                (const __attribute__((address_space(1))) void*)ga,            \
                (__attribute__((address_space(3))) void*)(As + buf_ +         \
                    seg_ * 1024 + lane * 16), 16, 0, 0);                      \
        }                                                                     \
    }

    // Assemble i32x8 fragment from 4x 8B loads (constant-index inserts only;
    // SROA-safe — R1/R2 lesson).
#define LOAD_FRAG(dst_, base_)                                                \
    {                                                                         \
        const int2 d0_ = *(const int2*)((base_));                             \
        const int2 d1_ = *(const int2*)((base_) + 128);                       \
        const int2 d2_ = *(const int2*)((base_) + 256);                       \
        const int2 d3_ = *(const int2*)((base_) + 384);                       \
        dst_[0] = d0_.x; dst_[1] = d0_.y;                                     \
        dst_[2] = d1_.x; dst_[3] = d1_.y;                                     \
        dst_[4] = d2_.x; dst_[5] = d2_.y;                                     \
        dst_[6] = d3_.x; dst_[7] = d3_.y;                                     \
    }

#define MXMFMA(a_, b_, c_)                                                    \
    __builtin_amdgcn_mfma_scale_f32_32x32x64_f8f6f4(                          \
        (a_), (b_), (c_), 0, 0, 0, 0x7F7F7F7F, 0, 0x7F7F7F7F)

    // Prologue: fill depth-2 DMA pipe + load B(0) into registers.
    // FIFO: DMA(0) 2, DMA(1) 2, B(0) 8 = 12 -> vmcnt(10) retires DMA(0).
    DMA_STAGE(0);
    DMA_STAGE(1);
    i32x8 bc0, bc1, bn0, bn1;
    LOAD_FRAG(bc0, b_frag);
    LOAD_FRAG(bc1, b_frag + 32768);
    asm volatile("s_waitcnt vmcnt(10)" ::: "memory");
    __builtin_amdgcn_s_barrier();

    #pragma unroll
    for (int st = 0; st < 16; st++) {
        const int buf = (st % 3) * 8192;

        // B prefetch for st+1 — issued first, consumed next stage.
        if (st < 15) {
            const int koff_n = (st + 1) * 1024;
            LOAD_FRAG(bn0, b_frag + koff_n);
            LOAD_FRAG(bn1, b_frag + 32768 + koff_n);
        }
        __builtin_amdgcn_sched_barrier(0);   // pin B prefetch above DMA

        if (st < 14) DMA_STAGE(st + 2);      // depth-2 prefetch

        // Compute stage st from buf with in-register B(st).
        __builtin_amdgcn_s_setprio(1);
        #pragma unroll
        for (int am = 0; am < 2; am++) {
            i32x8 af;
            LOAD_FRAG(af, As + buf + (wm * 4 + am * 2) * 1024 + a_off);
            acc[am][0] = MXMFMA(af, bc0, acc[am][0]);
            acc[am][1] = MXMFMA(af, bc1, acc[am][1]);
        }
        __builtin_amdgcn_s_setprio(0);

        // Stage boundary: counted wait retires DMA(st+1) only; B(st+1) and
        // DMA(st+2) stay in flight across the barrier. st==14: vmcnt(8)
        // (FIFO = DMA(15) 2 + B(15) 8; no DMA(16)).
        if (st < 15) {
            __builtin_amdgcn_sched_barrier(0);
            if (st < 14) {
                asm volatile("s_waitcnt vmcnt(10)" ::: "memory");
            } else {
                asm volatile("s_waitcnt vmcnt(8)" ::: "memory");
            }
            __builtin_amdgcn_s_barrier();
            __builtin_amdgcn_sched_barrier(0);
            bc0 = bn0; bc1 = bn1;   // static names; unrolled -> renamed away
        }
    }
#undef DMA_STAGE
#undef LOAD_FRAG
#undef MXMFMA

    __syncthreads();

    // Epilogue, 32x32 C/D layout: col = lane&31, row = (r&3)+8*(r>>2)+4*hi.
    #pragma unroll
    for (int an = 0; an < 2; an++) {
        float v = 3.4e38f;
        #pragma unroll
        for (int am = 0; am < 2; am++) {
            const int rbase = wm * 64 + am * 32 + hi * 4;
            f32x16 c = acc[am][an];
            #pragma unroll
            for (int r = 0; r < 16; r++) {
                const int row = (r & 3) + 8 * (r >> 2);
                v = fminf(v, zsq_s[rbase + row] - 2.f * c[r]);
            }
        }
        v = fminf(v, __shfl_xor(v, 32, 64));
        if (hi == 0) colmin[wm][wn * 64 + an * 32 + (lane & 31)] = v;
    }
    __syncthreads();
    if (t < 128) {
        const float m = fminf(colmin[0][t], colmin[1][t]);
        atomicMin(&min_enc[bx * 128 + t], enc_f32(m));
    }
}

// ---------------------------------------------------------------------------
// finalize: mean_j (dec(min_enc[j]) + esq[j]) -> single fp32 scalar.
// ---------------------------------------------------------------------------
__global__ __launch_bounds__(256) void finalize_kernel(
    const unsigned* __restrict__ min_enc, const float* __restrict__ esq,
    float* __restrict__ out) {
    const int t = threadIdx.x;
    float s = 0.f;
    #pragma unroll
    for (int i = 0; i < M_CODES / 256; i++) {
        const int j = i * 256 + t;
        s += dec_f32(min_enc[j]) + esq[j];
    }
    #pragma unroll
    for (int off = 1; off < 64; off <<= 1) s += __shfl_xor(s, off, 64);
    __shared__ float red[4];
    if ((t & 63) == 0) red[t >> 6] = s;
    __syncthreads();
    if (t == 0) out[0] = (red[0] + red[1] + red[2] + red[3]) * (1.f / M_CODES);
}

extern "C" void kernel_launch(void* const* d_in, const int* in_sizes, int n_in,
                              void* d_out, int out_size, void* d_ws, size_t ws_size,
                              hipStream_t stream) {
    (void)in_sizes; (void)n_in; (void)out_size; (void)ws_size;
    const float* z = (const float*)d_in[0];
    const float* e = (const float*)d_in[1];
    char* ws = (char*)d_ws;
    uint8_t* zb = (uint8_t*)ws;                                          // 4 MB
    uint8_t* eb = (uint8_t*)(ws + ((size_t)4 << 20));                    // 4 MB
    float* zsq = (float*)(ws + ((size_t)8 << 20));                       // 16 KB
    float* esq = (float*)(ws + ((size_t)8 << 20) + 16384);               // 16 KB
    unsigned* min_enc = (unsigned*)(ws + ((size_t)8 << 20) + 32768);     // 16 KB

    prep_kernel<<<dim3(512), dim3(256), 0, stream>>>(
        z, e, zb, eb, zsq, esq, min_enc);
    gemm_min_kernel<<<dim3(32, 32), dim3(256), 0, stream>>>(
        zb, eb, zsq, min_enc);
    finalize_kernel<<<dim3(1), dim3(256), 0, stream>>>(min_enc, esq, (float*)d_out);
}

// Round 9
// 103.082 us; speedup vs baseline: 1.7632x; 1.7632x over previous
//
#include <hip/hip_runtime.h>
#include <hip/hip_bf16.h>
#include <stdint.h>

#define N_PTS   4096
#define M_CODES 4096
#define ZDIM    1024
// fp8 tiled layout: elem (r,k) at seg(rb)*16384 + kg*128 + r16*8 + ke  (BYTES)
//   rb=r>>4, r16=r&15, kg=k>>3, ke=k&7. Chunk (rb,kg) = 16 rows x 8 k = 128 B.
//   Seg = 16 rows x 1024 k x 1 B = 16 KB.

typedef __attribute__((ext_vector_type(4)))  float f32x4;
typedef __attribute__((ext_vector_type(16))) float f32x16;
typedef __attribute__((ext_vector_type(8)))  int   i32x8;

__device__ __forceinline__ unsigned enc_f32(float f) {
    unsigned u = __float_as_uint(f);
    return (u & 0x80000000u) ? ~u : (u | 0x80000000u);
}
__device__ __forceinline__ float dec_f32(unsigned e) {
    unsigned u = (e & 0x80000000u) ? (e ^ 0x80000000u) : ~e;
    return __uint_as_float(u);
}

// ---------------------------------------------------------------------------
// prep: fp32 -> fp8 e4m3 (OCP) + tiled layout + row sum-of-squares.
// R9 change: LOAD-ALL-THEN-PROCESS. The old loop interleaved the dependent
// shfl-reduce chain between the 16 global loads; at 2 blocks/CU, if the
// scheduler doesn't batch them the loads serialize on ~900-cyc HBM latency
// (~12-15 µs vs the ~5.4 µs BW floor for 32 MB). Loading all 16 float4
// into a static-indexed array (64 VGPR, SROA-safe) guarantees 16
// outstanding loads per thread. One block = 16 rows. grid 512.
// ---------------------------------------------------------------------------
#define PREP_PITCH_B 1040   // bytes per LDS row: 1024 + 16 pad
__global__ __launch_bounds__(256) void prep_kernel(
    const float* __restrict__ z, const float* __restrict__ e,
    uint8_t* __restrict__ zb, uint8_t* __restrict__ eb,
    float* __restrict__ zsq, float* __restrict__ esq,
    unsigned* __restrict__ min_enc) {
    __shared__ uint8_t tile[16 * PREP_PITCH_B];   // ~16.6 KB
    __shared__ float redbuf[16 * 4];

    const int t = threadIdx.x;
    const int b = blockIdx.x;
    if (b < 16) min_enc[b * 256 + t] = 0xFFFFFFFFu;

    const bool is_z = b < 256;
    const int rb = b & 255;
    const float* src = (is_z ? z : e) + (size_t)rb * 16 * ZDIM;
    uint8_t* dst = (is_z ? zb : eb) + (size_t)rb * 16384;   // 16 KB seg
    const int w = t >> 6, lane = t & 63;

    // Phase 0: issue ALL 16 row loads (static indices -> registers).
    float4 v[16];
    #pragma unroll
    for (int it = 0; it < 16; it++)
        v[it] = reinterpret_cast<const float4*>(src + (size_t)it * ZDIM)[t];

    // Phase 1: pack 4 floats -> 4 fp8 into LDS; fp32 row sums (proven
    // reduction: wave shfl tree, redbuf[it*4+w]).
    #pragma unroll
    for (int it = 0; it < 16; it++) {
        int pk = 0;
        pk = __builtin_amdgcn_cvt_pk_fp8_f32(v[it].x, v[it].y, pk, false);
        pk = __builtin_amdgcn_cvt_pk_fp8_f32(v[it].z, v[it].w, pk, true);
        *reinterpret_cast<int*>(&tile[it * PREP_PITCH_B + t * 4]) = pk;
        float s = v[it].x * v[it].x + v[it].y * v[it].y +
                  v[it].z * v[it].z + v[it].w * v[it].w;
        #pragma unroll
        for (int off = 1; off < 64; off <<= 1) s += __shfl_xor(s, off, 64);
        if (lane == 0) redbuf[it * 4 + w] = s;
    }
    __syncthreads();

    // Phase 2: transpose-store to tiled global (chunk c -> dst + c*8, linear).
    #pragma unroll
    for (int it2 = 0; it2 < 8; it2++) {
        const int c = it2 * 256 + t;          // 0..2047
        const int kg = c >> 4, r16 = c & 15;
        const unsigned long long val = *reinterpret_cast<const unsigned long long*>(
            &tile[r16 * PREP_PITCH_B + kg * 8]);
        *reinterpret_cast<unsigned long long*>(&dst[(size_t)c * 8]) = val;
    }
    if (t < 16) {
        float sq = redbuf[t * 4] + redbuf[t * 4 + 1] +
                   redbuf[t * 4 + 2] + redbuf[t * 4 + 3];
        const int row = rb * 16 + t;
        if (is_z) zsq[row] = sq; else esq[row] = sq;
    }
}

// ---------------------------------------------------------------------------
// gemm_min: R7 champion BIT-EXACT (32x32x64 MX, 16 stages, 3 x 8 KB triple
// buffer, depth-2 DMA, counted `s_waitcnt vmcnt(2)` + raw s_barrier
// boundaries, B-loads-first pinning) + ONE zero-register addition:
// T5 s_setprio(1/0) around the per-stage compute cluster (this structure
// has the counted-vmcnt role-split where T5 measured +21-39%; R8 bundled
// it with a spilling change so it was never isolated).
// R8 hard rule: NO new live registers in the K-loop — every +8..16 reg
// attempt (R2/R6/R8) tripped the 128-reg quantum and spilled wholesale.
// ---------------------------------------------------------------------------
__global__ __launch_bounds__(256, 4) void gemm_min_kernel(
    const uint8_t* __restrict__ zb, const uint8_t* __restrict__ eb,
    const float* __restrict__ zsq, unsigned* __restrict__ min_enc) {
    __shared__ __align__(16) uint8_t As[3 * 8192];   // 3 bufs x (8 segs x 1 KB)
    __shared__ float zsq_s[128];
    __shared__ float colmin[2][128];

    const int t = threadIdx.x;        // 0..255
    const int bx = blockIdx.x;        // code (col) block
    const int by = blockIdx.y;        // point (row) block
    const int lane = t & 63;
    const int w = t >> 6;             // 0..3
    const int wm = w >> 1, wn = w & 1;
    const int hi = lane >> 5;         // K-half selector (and C/D row offset)

    if (t < 128) zsq_s[t] = zsq[by * 128 + t];

    f32x16 acc[2][2];
    #pragma unroll
    for (int i = 0; i < 2; i++)
        #pragma unroll
        for (int j = 0; j < 2; j++)
            #pragma unroll
            for (int r = 0; r < 16; r++) acc[i][j][r] = 0.f;

    const size_t a_seg0 = (size_t)(by * 8) * 16384;

    // Per-lane operand offset within a seg's 1 KB K-stage window:
    // lane l: k = (l>>5)*32 + p*8 + ke -> (l>>5)*512 + p*128 + (l&15)*8;
    // rows 16..31 of the 32-row block live one seg over (seg_sel).
    const int seg_sel = (lane & 31) >> 4;
    const int op_off  = hi * 512 + (lane & 15) * 8;
    const int a_off   = seg_sel * 1024 + op_off;

    // B (global): wave wn's 64-col panel; an adds 2 segs (32 KB).
    const uint8_t* b_frag =
        eb + (size_t)(bx * 8 + wn * 4 + seg_sel) * 16384 + op_off;

    // A staging per stage: 8 segs x 1 KB runs (seg's K-window st*1024).
    // 2 instrs x 256 thr x 16 B = 8 KB. Instr j: wave w -> seg j*4+w.
#define DMA_STAGE(st_)                                                        \
    {                                                                         \
        const int buf_ = ((st_) % 3) * 8192;                                  \
        _Pragma("unroll")                                                     \
        for (int j = 0; j < 2; j++) {                                         \
            const int seg_ = j * 4 + w;                                       \
            const uint8_t* ga = zb + a_seg0 + (size_t)seg_ * 16384 +          \
                (st_) * 1024 + lane * 16;                                     \
            __builtin_amdgcn_global_load_lds(                                 \
                (const __attribute__((address_space(1))) void*)ga,            \
                (__attribute__((address_space(3))) void*)(As + buf_ +         \
                    seg_ * 1024 + lane * 16), 16, 0, 0);                      \
        }                                                                     \
    }

    // Assemble i32x8 fragment from 4x 8B loads (constant-index inserts only;
    // SROA-safe — R1/R2 lesson).
#define LOAD_FRAG(dst_, base_)                                                \
    {                                                                         \
        const int2 d0_ = *(const int2*)((base_));                             \
        const int2 d1_ = *(const int2*)((base_) + 128);                       \
        const int2 d2_ = *(const int2*)((base_) + 256);                       \
        const int2 d3_ = *(const int2*)((base_) + 384);                       \
        dst_[0] = d0_.x; dst_[1] = d0_.y;                                     \
        dst_[2] = d1_.x; dst_[3] = d1_.y;                                     \
        dst_[4] = d2_.x; dst_[5] = d2_.y;                                     \
        dst_[6] = d3_.x; dst_[7] = d3_.y;                                     \
    }

#define MXMFMA(a_, b_, c_)                                                    \
    __builtin_amdgcn_mfma_scale_f32_32x32x64_f8f6f4(                          \
        (a_), (b_), (c_), 0, 0, 0, 0x7F7F7F7F, 0, 0x7F7F7F7F)

    // Prologue: fill depth-2 pipe; wait DMA(0) only (DMA(1) stays in flight).
    DMA_STAGE(0);
    DMA_STAGE(1);
    asm volatile("s_waitcnt vmcnt(2)" ::: "memory");
    __builtin_amdgcn_s_barrier();

    #pragma unroll
    for (int st = 0; st < 16; st++) {
        const int buf = (st % 3) * 8192;
        const int koff = st * 1024;

        // B fragments (K=64, both an panels) — FIRST, so their compiler
        // waits never drain the DMA prefetch queue.
        i32x8 bf0, bf1;
        LOAD_FRAG(bf0, b_frag + koff);
        LOAD_FRAG(bf1, b_frag + 32768 + koff);
        __builtin_amdgcn_sched_barrier(0);   // pin B loads above DMA

        if (st < 14) DMA_STAGE(st + 2);      // depth-2 prefetch

        // Compute stage st from buf: stream A fragments, 2 MX MFMAs each.
        // T5: raise wave priority through the compute cluster (0 regs).
        __builtin_amdgcn_s_setprio(1);
        #pragma unroll
        for (int am = 0; am < 2; am++) {
            i32x8 af;
            LOAD_FRAG(af, As + buf + (wm * 4 + am * 2) * 1024 + a_off);
            acc[am][0] = MXMFMA(af, bf0, acc[am][0]);
            acc[am][1] = MXMFMA(af, bf1, acc[am][1]);
        }
        __builtin_amdgcn_s_setprio(0);

        // Stage boundary: counted wait (DMA(st+2) stays in flight), raw
        // barrier. st==14: drain DMA(15) fully (no DMA(16) exists).
        if (st < 15) {
            __builtin_amdgcn_sched_barrier(0);
            if (st < 14) {
                asm volatile("s_waitcnt vmcnt(2)" ::: "memory");
            } else {
                asm volatile("s_waitcnt vmcnt(0)" ::: "memory");
            }
            __builtin_amdgcn_s_barrier();
            __builtin_amdgcn_sched_barrier(0);
        }
    }
#undef DMA_STAGE
#undef LOAD_FRAG
#undef MXMFMA

    __syncthreads();

    // Epilogue, 32x32 C/D layout: col = lane&31, row = (r&3)+8*(r>>2)+4*hi.
    #pragma unroll
    for (int an = 0; an < 2; an++) {
        float v = 3.4e38f;
        #pragma unroll
        for (int am = 0; am < 2; am++) {
            const int rbase = wm * 64 + am * 32 + hi * 4;
            f32x16 c = acc[am][an];
            #pragma unroll
            for (int r = 0; r < 16; r++) {
                const int row = (r & 3) + 8 * (r >> 2);
                v = fminf(v, zsq_s[rbase + row] - 2.f * c[r]);
            }
        }
        v = fminf(v, __shfl_xor(v, 32, 64));
        if (hi == 0) colmin[wm][wn * 64 + an * 32 + (lane & 31)] = v;
    }
    __syncthreads();
    if (t < 128) {
        const float m = fminf(colmin[0][t], colmin[1][t]);
        atomicMin(&min_enc[bx * 128 + t], enc_f32(m));
    }
}

// ---------------------------------------------------------------------------
// finalize: mean_j (dec(min_enc[j]) + esq[j]) -> single fp32 scalar.
// R9: uint4/float4 loads -> 4 serial round trips instead of 16 (1 block,
// latency-bound; min_enc/esq are L2-hot right after gemm). Sum-order change
// is far inside the task tolerance.
// ---------------------------------------------------------------------------
__global__ __launch_bounds__(256) void finalize_kernel(
    const unsigned* __restrict__ min_enc, const float* __restrict__ esq,
    float* __restrict__ out) {
    const int t = threadIdx.x;
    float s = 0.f;
    #pragma unroll
    for (int i = 0; i < M_CODES / (256 * 4); i++) {
        const int j4 = i * 256 + t;
        const uint4  me = reinterpret_cast<const uint4*>(min_enc)[j4];
        const float4 eq = reinterpret_cast<const float4*>(esq)[j4];
        s += (dec_f32(me.x) + eq.x) + (dec_f32(me.y) + eq.y) +
             (dec_f32(me.z) + eq.z) + (dec_f32(me.w) + eq.w);
    }
    #pragma unroll
    for (int off = 1; off < 64; off <<= 1) s += __shfl_xor(s, off, 64);
    __shared__ float red[4];
    if ((t & 63) == 0) red[t >> 6] = s;
    __syncthreads();
    if (t == 0) out[0] = (red[0] + red[1] + red[2] + red[3]) * (1.f / M_CODES);
}

extern "C" void kernel_launch(void* const* d_in, const int* in_sizes, int n_in,
                              void* d_out, int out_size, void* d_ws, size_t ws_size,
                              hipStream_t stream) {
    (void)in_sizes; (void)n_in; (void)out_size; (void)ws_size;
    const float* z = (const float*)d_in[0];
    const float* e = (const float*)d_in[1];
    char* ws = (char*)d_ws;
    uint8_t* zb = (uint8_t*)ws;                                          // 4 MB
    uint8_t* eb = (uint8_t*)(ws + ((size_t)4 << 20));                    // 4 MB
    float* zsq = (float*)(ws + ((size_t)8 << 20));                       // 16 KB
    float* esq = (float*)(ws + ((size_t)8 << 20) + 16384);               // 16 KB
    unsigned* min_enc = (unsigned*)(ws + ((size_t)8 << 20) + 32768);     // 16 KB

    prep_kernel<<<dim3(512), dim3(256), 0, stream>>>(
        z, e, zb, eb, zsq, esq, min_enc);
    gemm_min_kernel<<<dim3(32, 32), dim3(256), 0, stream>>>(
        zb, eb, zsq, min_enc);
    finalize_kernel<<<dim3(1), dim3(256), 0, stream>>>(min_enc, esq, (float*)d_out);
}

// Round 10
// 102.078 us; speedup vs baseline: 1.7806x; 1.0098x over previous
//
#include <hip/hip_runtime.h>
#include <hip/hip_bf16.h>
#include <stdint.h>

#define N_PTS   4096
#define M_CODES 4096
#define ZDIM    1024
// fp8 tiled layout: elem (r,k) at seg(rb)*16384 + kg*128 + r16*8 + ke  (BYTES)
//   rb=r>>4, r16=r&15, kg=k>>3, ke=k&7. Chunk (rb,kg) = 16 rows x 8 k = 128 B.
//   Seg = 16 rows x 1024 k x 1 B = 16 KB.

typedef __attribute__((ext_vector_type(4)))  float f32x4;
typedef __attribute__((ext_vector_type(16))) float f32x16;
typedef __attribute__((ext_vector_type(8)))  int   i32x8;

__device__ __forceinline__ unsigned enc_f32(float f) {
    unsigned u = __float_as_uint(f);
    return (u & 0x80000000u) ? ~u : (u | 0x80000000u);
}
__device__ __forceinline__ float dec_f32(unsigned e) {
    unsigned u = (e & 0x80000000u) ? (e ^ 0x80000000u) : ~e;
    return __uint_as_float(u);
}

// ---------------------------------------------------------------------------
// prep: fp32 -> fp8 e4m3 (OCP) + tiled layout + row sum-of-squares.
// R9 structure (champion): load-all-16-then-process (16 outstanding loads/
// thread), proven shfl reduction, transpose-store via LDS. grid 512.
// ---------------------------------------------------------------------------
#define PREP_PITCH_B 1040   // bytes per LDS row: 1024 + 16 pad
__global__ __launch_bounds__(256) void prep_kernel(
    const float* __restrict__ z, const float* __restrict__ e,
    uint8_t* __restrict__ zb, uint8_t* __restrict__ eb,
    float* __restrict__ zsq, float* __restrict__ esq,
    unsigned* __restrict__ min_enc) {
    __shared__ uint8_t tile[16 * PREP_PITCH_B];   // ~16.6 KB
    __shared__ float redbuf[16 * 4];

    const int t = threadIdx.x;
    const int b = blockIdx.x;
    if (b < 16) min_enc[b * 256 + t] = 0xFFFFFFFFu;

    const bool is_z = b < 256;
    const int rb = b & 255;
    const float* src = (is_z ? z : e) + (size_t)rb * 16 * ZDIM;
    uint8_t* dst = (is_z ? zb : eb) + (size_t)rb * 16384;   // 16 KB seg
    const int w = t >> 6, lane = t & 63;

    // Phase 0: issue ALL 16 row loads (static indices -> registers).
    float4 v[16];
    #pragma unroll
    for (int it = 0; it < 16; it++)
        v[it] = reinterpret_cast<const float4*>(src + (size_t)it * ZDIM)[t];

    // Phase 1: pack 4 floats -> 4 fp8 into LDS; fp32 row sums.
    #pragma unroll
    for (int it = 0; it < 16; it++) {
        int pk = 0;
        pk = __builtin_amdgcn_cvt_pk_fp8_f32(v[it].x, v[it].y, pk, false);
        pk = __builtin_amdgcn_cvt_pk_fp8_f32(v[it].z, v[it].w, pk, true);
        *reinterpret_cast<int*>(&tile[it * PREP_PITCH_B + t * 4]) = pk;
        float s = v[it].x * v[it].x + v[it].y * v[it].y +
                  v[it].z * v[it].z + v[it].w * v[it].w;
        #pragma unroll
        for (int off = 1; off < 64; off <<= 1) s += __shfl_xor(s, off, 64);
        if (lane == 0) redbuf[it * 4 + w] = s;
    }
    __syncthreads();

    // Phase 2: transpose-store to tiled global (chunk c -> dst + c*8, linear).
    #pragma unroll
    for (int it2 = 0; it2 < 8; it2++) {
        const int c = it2 * 256 + t;          // 0..2047
        const int kg = c >> 4, r16 = c & 15;
        const unsigned long long val = *reinterpret_cast<const unsigned long long*>(
            &tile[r16 * PREP_PITCH_B + kg * 8]);
        *reinterpret_cast<unsigned long long*>(&dst[(size_t)c * 8]) = val;
    }
    if (t < 16) {
        float sq = redbuf[t * 4] + redbuf[t * 4 + 1] +
                   redbuf[t * 4 + 2] + redbuf[t * 4 + 3];
        const int row = rb * 16 + t;
        if (is_z) zsq[row] = sq; else esq[row] = sq;
    }
}

// ---------------------------------------------------------------------------
// gemm_min: R9 champion structure (32x32x64 MX, 16 stages, triple buffer,
// depth-2 DMA, counted-vmcnt + raw s_barrier, setprio around MFMA) with
// B MOVED TO THE LDS/DMA STREAM.
// R9 analysis: per-CU stage cost was L2-bound, not MFMA-bound — b_frag is
// wm-independent, so wave pairs loaded identical B bytes (256 KB/block of
// B vs 128 KB distinct; L2 term ~1700 cyc vs MFMA ~1100). Staging B via
// global_load_lds alongside A: (a) halves B global traffic -> L2 term
// ~1140 cyc, balanced with MFMA; (b) B consumed by ds_read (same proven
// conflict-free fragment pattern as A, keyed by wn); (c) frees the 16
// long-lived bf VGPRs (R8 hard rule respected: demand ~108 < 128).
// Cost: LDS 24 -> 48 KB => 3 blocks/CU — acceptable now that counted-vmcnt
// amortizes the per-stage stall (12 waves/CU cover ~900-cyc stages).
// vmcnt bookkeeping: 4 DMA instrs/stage (2 A + 2 B), depth 2:
//   prologue DMA(0)+DMA(1)=8 outstanding -> vmcnt(4) retires DMA(0);
//   boundary vmcnt(4) retires DMA(st+1), keeps DMA(st+2) in flight;
//   st==14 boundary vmcnt(0) (no DMA(16) exists).
// ---------------------------------------------------------------------------
__global__ __launch_bounds__(256, 4) void gemm_min_kernel(
    const uint8_t* __restrict__ zb, const uint8_t* __restrict__ eb,
    const float* __restrict__ zsq, unsigned* __restrict__ min_enc) {
    __shared__ __align__(16) uint8_t As[3 * 8192];   // 3 bufs x (8 segs x 1 KB)
    __shared__ __align__(16) uint8_t Bs[3 * 8192];   // 3 bufs x (8 segs x 1 KB)
    __shared__ float zsq_s[128];
    __shared__ float colmin[2][128];

    const int t = threadIdx.x;        // 0..255
    const int bx = blockIdx.x;        // code (col) block
    const int by = blockIdx.y;        // point (row) block
    const int lane = t & 63;
    const int w = t >> 6;             // 0..3
    const int wm = w >> 1, wn = w & 1;
    const int hi = lane >> 5;         // K-half selector (and C/D row offset)

    if (t < 128) zsq_s[t] = zsq[by * 128 + t];

    f32x16 acc[2][2];
    #pragma unroll
    for (int i = 0; i < 2; i++)
        #pragma unroll
        for (int j = 0; j < 2; j++)
            #pragma unroll
            for (int r = 0; r < 16; r++) acc[i][j][r] = 0.f;

    const size_t a_seg0 = (size_t)(by * 8) * 16384;
    const size_t b_seg0 = (size_t)(bx * 8) * 16384;

    // Per-lane operand offset within a seg's 1 KB K-stage window:
    // lane l: k = (l>>5)*32 + p*8 + ke -> (l>>5)*512 + p*128 + (l&15)*8;
    // rows 16..31 of the 32-row block live one seg over (seg_sel).
    const int seg_sel = (lane & 31) >> 4;
    const int op_off  = hi * 512 + (lane & 15) * 8;
    const int a_off   = seg_sel * 1024 + op_off;   // also B's in-buf offset

    // A+B staging per stage: 8 A segs + 8 B segs x 1 KB runs (K-window
    // st*1024). 4 instrs x 256 thr x 16 B = 16 KB. Instr j: wave w ->
    // seg j*4+w, for A then B (FIFO order A0,B0,A1,B1 — 4 per stage).
#define DMA_STAGE(st_)                                                        \
    {                                                                         \
        const int buf_ = ((st_) % 3) * 8192;                                  \
        _Pragma("unroll")                                                     \
        for (int j = 0; j < 2; j++) {                                         \
            const int seg_ = j * 4 + w;                                       \
            const uint8_t* ga = zb + a_seg0 + (size_t)seg_ * 16384 +          \
                (st_) * 1024 + lane * 16;                                     \
            __builtin_amdgcn_global_load_lds(                                 \
                (const __attribute__((address_space(1))) void*)ga,            \
                (__attribute__((address_space(3))) void*)(As + buf_ +         \
                    seg_ * 1024 + lane * 16), 16, 0, 0);                      \
            const uint8_t* gb = eb + b_seg0 + (size_t)seg_ * 16384 +          \
                (st_) * 1024 + lane * 16;                                     \
            __builtin_amdgcn_global_load_lds(                                 \
                (const __attribute__((address_space(1))) void*)gb,            \
                (__attribute__((address_space(3))) void*)(Bs + buf_ +         \
                    seg_ * 1024 + lane * 16), 16, 0, 0);                      \
        }                                                                     \
    }

    // Assemble i32x8 fragment from 4x 8B loads (constant-index inserts only;
    // SROA-safe — R1/R2 lesson). Works for LDS pointers (ds_read_b64).
#define LOAD_FRAG(dst_, base_)                                                \
    {                                                                         \
        const int2 d0_ = *(const int2*)((base_));                             \
        const int2 d1_ = *(const int2*)((base_) + 128);                       \
        const int2 d2_ = *(const int2*)((base_) + 256);                       \
        const int2 d3_ = *(const int2*)((base_) + 384);                       \
        dst_[0] = d0_.x; dst_[1] = d0_.y;                                     \
        dst_[2] = d1_.x; dst_[3] = d1_.y;                                     \
        dst_[4] = d2_.x; dst_[5] = d2_.y;                                     \
        dst_[6] = d3_.x; dst_[7] = d3_.y;                                     \
    }

#define MXMFMA(a_, b_, c_)                                                    \
    __builtin_amdgcn_mfma_scale_f32_32x32x64_f8f6f4(                          \
        (a_), (b_), (c_), 0, 0, 0, 0x7F7F7F7F, 0, 0x7F7F7F7F)

    // Prologue: fill depth-2 pipe; wait DMA(0) only (DMA(1) stays in flight).
    DMA_STAGE(0);
    DMA_STAGE(1);
    asm volatile("s_waitcnt vmcnt(4)" ::: "memory");
    __builtin_amdgcn_s_barrier();

    #pragma unroll
    for (int st = 0; st < 16; st++) {
        const int buf = (st % 3) * 8192;

        if (st < 14) DMA_STAGE(st + 2);      // depth-2 prefetch

        // B fragments from LDS (wn-keyed; pattern identical to A reads).
        i32x8 bf0, bf1;
        LOAD_FRAG(bf0, Bs + buf + (wn * 4 + 0) * 1024 + a_off);
        LOAD_FRAG(bf1, Bs + buf + (wn * 4 + 2) * 1024 + a_off);

        // Compute stage st: stream A fragments, 2 MX MFMAs each.
        // T5 setprio around the MFMA cluster (0 regs; proven structure).
        __builtin_amdgcn_s_setprio(1);
        #pragma unroll
        for (int am = 0; am < 2; am++) {
            i32x8 af;
            LOAD_FRAG(af, As + buf + (wm * 4 + am * 2) * 1024 + a_off);
            acc[am][0] = MXMFMA(af, bf0, acc[am][0]);
            acc[am][1] = MXMFMA(af, bf1, acc[am][1]);
        }
        __builtin_amdgcn_s_setprio(0);

        // Stage boundary: counted wait (DMA(st+2) stays in flight), raw
        // barrier. st==14: drain DMA(15) fully (no DMA(16) exists).
        if (st < 15) {
            __builtin_amdgcn_sched_barrier(0);
            if (st < 14) {
                asm volatile("s_waitcnt vmcnt(4)" ::: "memory");
            } else {
                asm volatile("s_waitcnt vmcnt(0)" ::: "memory");
            }
            __builtin_amdgcn_s_barrier();
            __builtin_amdgcn_sched_barrier(0);
        }
    }
#undef DMA_STAGE
#undef LOAD_FRAG
#undef MXMFMA

    __syncthreads();

    // Epilogue, 32x32 C/D layout: col = lane&31, row = (r&3)+8*(r>>2)+4*hi.
    #pragma unroll
    for (int an = 0; an < 2; an++) {
        float v = 3.4e38f;
        #pragma unroll
        for (int am = 0; am < 2; am++) {
            const int rbase = wm * 64 + am * 32 + hi * 4;
            f32x16 c = acc[am][an];
            #pragma unroll
            for (int r = 0; r < 16; r++) {
                const int row = (r & 3) + 8 * (r >> 2);
                v = fminf(v, zsq_s[rbase + row] - 2.f * c[r]);
            }
        }
        v = fminf(v, __shfl_xor(v, 32, 64));
        if (hi == 0) colmin[wm][wn * 64 + an * 32 + (lane & 31)] = v;
    }
    __syncthreads();
    if (t < 128) {
        const float m = fminf(colmin[0][t], colmin[1][t]);
        atomicMin(&min_enc[bx * 128 + t], enc_f32(m));
    }
}

// ---------------------------------------------------------------------------
// finalize: mean_j (dec(min_enc[j]) + esq[j]) -> single fp32 scalar.
// R9 structure: uint4/float4 loads, 4 iterations.
// ---------------------------------------------------------------------------
__global__ __launch_bounds__(256) void finalize_kernel(
    const unsigned* __restrict__ min_enc, const float* __restrict__ esq,
    float* __restrict__ out) {
    const int t = threadIdx.x;
    float s = 0.f;
    #pragma unroll
    for (int i = 0; i < M_CODES / (256 * 4); i++) {
        const int j4 = i * 256 + t;
        const uint4  me = reinterpret_cast<const uint4*>(min_enc)[j4];
        const float4 eq = reinterpret_cast<const float4*>(esq)[j4];
        s += (dec_f32(me.x) + eq.x) + (dec_f32(me.y) + eq.y) +
             (dec_f32(me.z) + eq.z) + (dec_f32(me.w) + eq.w);
    }
    #pragma unroll
    for (int off = 1; off < 64; off <<= 1) s += __shfl_xor(s, off, 64);
    __shared__ float red[4];
    if ((t & 63) == 0) red[t >> 6] = s;
    __syncthreads();
    if (t == 0) out[0] = (red[0] + red[1] + red[2] + red[3]) * (1.f / M_CODES);
}

extern "C" void kernel_launch(void* const* d_in, const int* in_sizes, int n_in,
                              void* d_out, int out_size, void* d_ws, size_t ws_size,
                              hipStream_t stream) {
    (void)in_sizes; (void)n_in; (void)out_size; (void)ws_size;
    const float* z = (const float*)d_in[0];
    const float* e = (const float*)d_in[1];
    char* ws = (char*)d_ws;
    uint8_t* zb = (uint8_t*)ws;                                          // 4 MB
    uint8_t* eb = (uint8_t*)(ws + ((size_t)4 << 20));                    // 4 MB
    float* zsq = (float*)(ws + ((size_t)8 << 20));                       // 16 KB
    float* esq = (float*)(ws + ((size_t)8 << 20) + 16384);               // 16 KB
    unsigned* min_enc = (unsigned*)(ws + ((size_t)8 << 20) + 32768);     // 16 KB

    prep_kernel<<<dim3(512), dim3(256), 0, stream>>>(
        z, e, zb, eb, zsq, esq, min_enc);
    gemm_min_kernel<<<dim3(32, 32), dim3(256), 0, stream>>>(
        zb, eb, zsq, min_enc);
    finalize_kernel<<<dim3(1), dim3(256), 0, stream>>>(min_enc, esq, (float*)d_out);
}